// Round 9
// baseline (1144.910 us; speedup 1.0000x reference)
//
#include <hip/hip_runtime.h>

#define PAD_IDX 0

typedef __attribute__((ext_vector_type(8))) short short8;
typedef __attribute__((ext_vector_type(4))) float f32x4;

// ---------- helpers ----------
__device__ __forceinline__ unsigned short f32_to_bf16_rne(float f) {
  unsigned int u = __builtin_bit_cast(unsigned int, f);
  u += 0x7FFFu + ((u >> 16) & 1u);
  return (unsigned short)(u >> 16);
}

__device__ __forceinline__ void load16_to_lds(const void* g, void* lds) {
  __builtin_amdgcn_global_load_lds(
      (const __attribute__((address_space(1))) unsigned int*)g,
      (__attribute__((address_space(3))) unsigned int*)lds,
      16, 0, 0);
}

// ---------- kernel 0: sentinel (only if ws too small) ----------
__global__ void sentinel_kernel(float* out) { out[0] = 1.0e6f; }

// ---------- kernel 1: merged xw + cvt (role by blockIdx) ----------
__global__ __launch_bounds__(256) void xwcvt_kernel(const int* __restrict__ tok,
                                                    const float* __restrict__ emb,
                                                    const float* __restrict__ Wx,
                                                    const float* __restrict__ bias,
                                                    float* __restrict__ xw,
                                                    const float* __restrict__ lmW,
                                                    unsigned short* __restrict__ lmW_bf) {
  int tid = threadIdx.x;
  if (blockIdx.x >= 1024) {
    const int n8 = 32000 * 1024 / 8;
    int stride = 512 * 256;
    for (int i = (blockIdx.x - 1024) * 256 + tid; i < n8; i += stride) {
      float4 a = ((const float4*)lmW)[2 * i];
      float4 b = ((const float4*)lmW)[2 * i + 1];
      ushort4 lo, hi;
      lo.x = f32_to_bf16_rne(a.x); lo.y = f32_to_bf16_rne(a.y);
      lo.z = f32_to_bf16_rne(a.z); lo.w = f32_to_bf16_rne(a.w);
      hi.x = f32_to_bf16_rne(b.x); hi.y = f32_to_bf16_rne(b.y);
      hi.z = f32_to_bf16_rne(b.z); hi.w = f32_to_bf16_rne(b.w);
      ((ushort4*)lmW_bf)[2 * i] = lo;
      ((ushort4*)lmW_bf)[2 * i + 1] = hi;
    }
    return;
  }
  __shared__ float At[32][68];
  __shared__ float Bt[32][68];
  __shared__ int stok[64];
  int tm = blockIdx.x & 63;
  int tn = blockIdx.x >> 6;
  int r0 = tm * 64, j0 = tn * 64;
  if (tid < 64) stok[tid] = tok[r0 + tid];
  int tx = tid & 15, ty = tid >> 4;
  float acc[4][4] = {};
  for (int kt = 0; kt < 512; kt += 32) {
    __syncthreads();
    #pragma unroll
    for (int ii = 0; ii < 2; ++ii) {
      int idx = tid * 2 + ii;
      int m = idx >> 3, fv = idx & 7;
      float4 va = *(const float4*)&emb[(size_t)stok[m] * 512 + kt + fv * 4];
      float4 vb = *(const float4*)&Wx[(size_t)(j0 + m) * 512 + kt + fv * 4];
      At[fv * 4 + 0][m] = va.x; At[fv * 4 + 1][m] = va.y;
      At[fv * 4 + 2][m] = va.z; At[fv * 4 + 3][m] = va.w;
      Bt[fv * 4 + 0][m] = vb.x; Bt[fv * 4 + 1][m] = vb.y;
      Bt[fv * 4 + 2][m] = vb.z; Bt[fv * 4 + 3][m] = vb.w;
    }
    __syncthreads();
    #pragma unroll
    for (int k = 0; k < 32; ++k) {
      float4 a4 = *(const float4*)&At[k][ty * 4];
      float4 b4 = *(const float4*)&Bt[k][tx * 4];
      float av[4] = {a4.x, a4.y, a4.z, a4.w};
      float bv[4] = {b4.x, b4.y, b4.z, b4.w};
      #pragma unroll
      for (int i = 0; i < 4; ++i)
        #pragma unroll
        for (int jj = 0; jj < 4; ++jj) acc[i][jj] = fmaf(av[i], bv[jj], acc[i][jj]);
    }
  }
  #pragma unroll
  for (int i = 0; i < 4; ++i) {
    size_t row = (size_t)(r0 + ty * 4 + i) * 1024 + j0 + tx * 4;
    #pragma unroll
    for (int jj = 0; jj < 4; ++jj)
      xw[row + jj] = acc[i][jj] + bias[j0 + tx * 4 + jj];
  }
}

// ---------- kernel 3: recurrence (R9: ds_add_f32 acc + exchange store + race fix) ----------
// 256 WGs x 1024 thr. chain c = blk&15, wg g = blk>>4 (rows g*64..+63).
// Wave w = k-slice [w*64,w*64+64); lane l = row g*64+l, 16 named f32x4 weights.
// Per step: poll own slot (fused data+tag u64) -> wave-local LDS share ->
// FMA -> ds_add_f32 into parity accs[p][l] -> lgkm0+barrier -> wave0 reads
// accs (1 load, not 16), zeroes it, tanh, atomic_exchange hcomb (promptness),
// h_all store. Pad-path reads old h from OWN hcomb slot (fixes hs[g] race).
__global__ __launch_bounds__(1024, 4) void rec_kernel(const float* __restrict__ Wh,
                                                      const float* __restrict__ xw,
                                                      const int* __restrict__ tok,
                                                      unsigned long long* hcomb,  // [2][16][1024]
                                                      unsigned short* __restrict__ h_all) {
  int c = blockIdx.x & 15;
  int g = blockIdx.x >> 4;
  int tid = threadIdx.x;
  int w = tid >> 6;
  int l = tid & 63;
  int j = g * 64 + l;

  const float* wb = Wh + (size_t)j * 1024 + w * 64;
#define LDW(i) f32x4 w##i = *(const f32x4*)(wb + i * 4);
  LDW(0) LDW(1) LDW(2) LDW(3) LDW(4) LDW(5) LDW(6) LDW(7)
  LDW(8) LDW(9) LDW(10) LDW(11) LDW(12) LDW(13) LDW(14) LDW(15)
#undef LDW

  __shared__ float hs[16][64];
  __shared__ float accs[2][64];   // parity accumulators
  if (tid < 128) ((float*)accs)[tid] = 0.f;
  __syncthreads();

  unsigned long long* hc0 = hcomb + (size_t)c * 1024;
  unsigned long long* hc1 = hcomb + 16 * 1024 + (size_t)c * 1024;
  bool writer = (w == 0);

  for (int t = 0; t < 256; ++t) {
    int p = t & 1;
    unsigned long long* hcp = p ? hc1 : hc0;
    // writer prefetch (hides under the poll): xw, tok, own-row old h
    float xv = 0.f, oldh = 0.f;
    int tkn = 1;
    if (writer) {
      xv = xw[((size_t)c * 256 + t) * 1024 + j];
      tkn = tok[c * 256 + t];
      unsigned long long ov = __hip_atomic_load(hcp + j, __ATOMIC_RELAXED, __HIP_MEMORY_SCOPE_AGENT);
      oldh = __builtin_bit_cast(float, (unsigned int)ov);  // own prev store: tag==t guaranteed
    }
    // poll own slot: tag==t means step-t data present in the same 8B load
    unsigned long long* src = hcp + tid;
    unsigned long long v;
    int guard = 0;
    do {
      v = __hip_atomic_load(src, __ATOMIC_RELAXED, __HIP_MEMORY_SCOPE_AGENT);
      if ((unsigned int)(v >> 32) == (unsigned int)t) break;
      __builtin_amdgcn_s_sleep(1);
    } while (++guard < (1 << 20));  // fail loud (absmax), not hung
    hs[w][l] = __builtin_bit_cast(float, (unsigned int)v);
    __asm__ volatile("s_waitcnt lgkmcnt(0)" ::: "memory");  // wave-local share

    const float* hp = &hs[w][0];   // broadcast reads
    f32x4 a0 = {0.f, 0.f, 0.f, 0.f}, a1 = a0, a2 = a0, a3 = a0;
#define FMAI(i, acc) { f32x4 h4 = *(const f32x4*)(hp + i * 4); acc += w##i * h4; }
    FMAI(0, a0) FMAI(1, a1) FMAI(2, a2) FMAI(3, a3)
    FMAI(4, a0) FMAI(5, a1) FMAI(6, a2) FMAI(7, a3)
    FMAI(8, a0) FMAI(9, a1) FMAI(10, a2) FMAI(11, a3)
    FMAI(12, a0) FMAI(13, a1) FMAI(14, a2) FMAI(15, a3)
#undef FMAI
    f32x4 aa = (a0 + a1) + (a2 + a3);
    float partial = (aa[0] + aa[1]) + (aa[2] + aa[3]);
    __hip_atomic_fetch_add(&accs[p][l], partial, __ATOMIC_RELAXED, __HIP_MEMORY_SCOPE_WORKGROUP);
    __asm__ volatile("s_waitcnt lgkmcnt(0)\n\ts_barrier" ::: "memory");

    if (writer) {
      float s = accs[p][l];
      accs[p][l] = 0.f;  // reset for t+2 (t+1 barrier orders vs future adds)
      float hnew;
      if (tkn != PAD_IDX) {
        float pre = xv + s;
        float e = __builtin_amdgcn_exp2f(pre * 2.8853900817779268f);  // exp(2x)
        hnew = 1.0f - 2.0f / (e + 1.0f);                              // tanh(x)
      } else {
        hnew = oldh;
      }
      unsigned long long pv =
          ((unsigned long long)(unsigned int)(t + 1) << 32) |
          (unsigned long long)__builtin_bit_cast(unsigned int, hnew);
      (void)__hip_atomic_exchange((p ? hc0 : hc1) + j, pv,
                                  __ATOMIC_RELAXED, __HIP_MEMORY_SCOPE_AGENT);
      h_all[((size_t)c * 256 + t) * 1024 + j] = f32_to_bf16_rne(hnew);
    }
  }
}

// ---------- kernel 4: logits = h_all(bf16) @ lm_W(bf16)^T, f32 out ----------
// BM=256 BN=256 BK=64, 512 thr (8 waves 2Mx4N). 2 LDS stages, counted vmcnt(8).
// R9: tail dead-stage is 8 same-hot-line 16B loads (keeps vmcnt math, ~0 traffic
// vs 128KB/WG of dead full-tile reads).
__global__ __launch_bounds__(512) void gemm_kernel(const unsigned short* __restrict__ A,
                                                   const unsigned short* __restrict__ B,
                                                   float* __restrict__ C) {
  __shared__ unsigned short lds[2 * 32768];
  int tid = threadIdx.x;
  int lane = tid & 63, wave = tid >> 6;
  int bid = blockIdx.x;
  int wgid = (bid & 7) * 250 + (bid >> 3);   // bijective XCD swizzle (2000 = 8*250)
  int tm = wgid & 15, tn = wgid >> 4;
  int r0 = tm * 256, c0 = tn * 256;
  int wm = wave >> 2, wn = wave & 3;         // 2M x 4N

  auto STAGE = [&](int kt, int st) {
    unsigned short* bufA = (unsigned short*)lds + st * 32768;
    unsigned short* bufB = bufA + 16384;
    #pragma unroll
    for (int i = 0; i < 4; ++i) {
      int slot = i * 512 + tid;
      int row = slot >> 3, sg = slot & 7;
      int kg = sg ^ (row & 7);
      const unsigned short* ga = A + (size_t)(r0 + row) * 1024 + kt * 64 + kg * 8;
      load16_to_lds(ga, &bufA[(i * 512 + wave * 64) * 8]);
    }
    #pragma unroll
    for (int i = 0; i < 4; ++i) {
      int slot = i * 512 + tid;
      int row = slot >> 3, sg = slot & 7;
      int kg = sg ^ (row & 7);
      const unsigned short* gb = B + (size_t)(c0 + row) * 1024 + kt * 64 + kg * 8;
      load16_to_lds(gb, &bufB[(i * 512 + wave * 64) * 8]);
    }
  };

  f32x4 zero = {0.f, 0.f, 0.f, 0.f};
  f32x4 acc[8][4];
  #pragma unroll
  for (int i = 0; i < 8; ++i)
    #pragma unroll
    for (int jx = 0; jx < 4; ++jx) acc[i][jx] = zero;

  STAGE(0, 0);
  STAGE(1, 1);
  __asm__ volatile("s_waitcnt vmcnt(8)\n\ts_barrier" ::: "memory");  // tile0 landed

  for (int kt = 0; kt < 16; ++kt) {
    int st = kt & 1;
    const unsigned short* bufA = (const unsigned short*)lds + st * 32768;
    const unsigned short* bufB = bufA + 16384;

    short8 af[8][2], bf[4][2];
    #pragma unroll
    for (int kkb = 0; kkb < 2; ++kkb) {
      int kbyte = kkb * 64 + (lane >> 4) * 16;
      #pragma unroll
      for (int i = 0; i < 8; ++i) {
        int rowa = wm * 128 + i * 16 + (lane & 15);
        af[i][kkb] = *(const short8*)((const char*)bufA + rowa * 128 + (kbyte ^ ((rowa & 7) << 4)));
      }
      #pragma unroll
      for (int i = 0; i < 4; ++i) {
        int rowb = wn * 64 + i * 16 + (lane & 15);
        bf[i][kkb] = *(const short8*)((const char*)bufB + rowb * 128 + (kbyte ^ ((rowb & 7) << 4)));
      }
    }
    // all waves' ds_reads of this buffer must retire before restaging into it
    __asm__ volatile("s_waitcnt lgkmcnt(0)\n\ts_barrier" ::: "memory");
    if (kt < 14) {
      STAGE(kt + 2, st);
    } else {
      // dead-stage: 8 loads of one hot 16B line into the retired buffer (vmcnt math)
      unsigned short* dead = (unsigned short*)lds + st * 32768;
      #pragma unroll
      for (int i = 0; i < 8; ++i) load16_to_lds(A + (size_t)r0 * 1024, &dead[i * 8]);
    }
    __builtin_amdgcn_s_setprio(1);
    #pragma unroll
    for (int kkb = 0; kkb < 2; ++kkb)
      #pragma unroll
      for (int i = 0; i < 8; ++i)
        #pragma unroll
        for (int jx = 0; jx < 4; ++jx)
          acc[i][jx] = __builtin_amdgcn_mfma_f32_16x16x32_bf16(af[i][kkb], bf[jx][kkb], acc[i][jx], 0, 0, 0);
    __builtin_amdgcn_s_setprio(0);
    __asm__ volatile("s_waitcnt vmcnt(8)\n\ts_barrier" ::: "memory");
  }
  // drain ALL outstanding LDS-DMA before this WG can retire (LDS reassignment!)
  __asm__ volatile("s_waitcnt vmcnt(0)" ::: "memory");

  int rbase = r0 + wm * 128 + (lane >> 4) * 4;
  int cbase = c0 + wn * 64 + (lane & 15);
  #pragma unroll
  for (int i = 0; i < 8; ++i)
    #pragma unroll
    for (int jx = 0; jx < 4; ++jx)
      #pragma unroll
      for (int q = 0; q < 4; ++q)
        C[(size_t)(rbase + i * 16 + q) * 32000 + cbase + jx * 16] = acc[i][jx][q];
}

// ---------- launch ----------
extern "C" void kernel_launch(void* const* d_in, const int* in_sizes, int n_in,
                              void* d_out, int out_size, void* d_ws, size_t ws_size,
                              hipStream_t stream) {
  const int* tok = (const int*)d_in[0];
  const float* emb = (const float*)d_in[1];
  const float* Wx = (const float*)d_in[2];
  const float* Wh = (const float*)d_in[3];
  const float* bias = (const float*)d_in[4];
  const float* lmW = (const float*)d_in[5];
  float* out = (float*)d_out;

  const size_t OFF_LMW = 0;                       // bf16 lm_W: 65,536,000
  const size_t OFF_XW = 65536000;                 // f32 xw:   16,777,216
  const size_t OFF_HALL = OFF_XW + 16777216;      // bf16 h_all: 8,388,608
  const size_t OFF_HCMB = OFF_HALL + 8388608;     // u64 hcomb: 262,144
  const size_t NEED = OFF_HCMB + 262144;
  if (ws_size < NEED) {
    sentinel_kernel<<<1, 1, 0, stream>>>(out);
    return;
  }
  char* ws = (char*)d_ws;
  unsigned short* lmW_bf = (unsigned short*)(ws + OFF_LMW);
  float* xw = (float*)(ws + OFF_XW);
  unsigned short* h_all = (unsigned short*)(ws + OFF_HALL);
  unsigned long long* hcomb = (unsigned long long*)(ws + OFF_HCMB);

  // tags must restart at 0 EVERY call (graph replay!)
  hipMemsetAsync(ws + OFF_HCMB, 0, 262144, stream);
  xwcvt_kernel<<<1536, 256, 0, stream>>>(tok, emb, Wx, bias, xw, lmW, lmW_bf);
  rec_kernel<<<256, 1024, 0, stream>>>(Wh, xw, tok, hcomb, h_all);
  gemm_kernel<<<2000, 512, 0, stream>>>(h_all, lmW_bf, out);
}

// Round 10
// 879.052 us; speedup vs baseline: 1.3024x; 1.3024x over previous
//
#include <hip/hip_runtime.h>

#define PAD_IDX 0

typedef __attribute__((ext_vector_type(8))) short short8;
typedef __attribute__((ext_vector_type(4))) float f32x4;

// ---------- helpers ----------
__device__ __forceinline__ unsigned short f32_to_bf16_rne(float f) {
  unsigned int u = __builtin_bit_cast(unsigned int, f);
  u += 0x7FFFu + ((u >> 16) & 1u);
  return (unsigned short)(u >> 16);
}

__device__ __forceinline__ void load16_to_lds(const void* g, void* lds) {
  __builtin_amdgcn_global_load_lds(
      (const __attribute__((address_space(1))) unsigned int*)g,
      (__attribute__((address_space(3))) unsigned int*)lds,
      16, 0, 0);
}

// ---------- kernel 0: sentinel (only if ws too small) ----------
__global__ void sentinel_kernel(float* out) { out[0] = 1.0e6f; }

// ---------- kernel 1: merged xw + cvt (role by blockIdx) ----------
__global__ __launch_bounds__(256) void xwcvt_kernel(const int* __restrict__ tok,
                                                    const float* __restrict__ emb,
                                                    const float* __restrict__ Wx,
                                                    const float* __restrict__ bias,
                                                    float* __restrict__ xw,
                                                    const float* __restrict__ lmW,
                                                    unsigned short* __restrict__ lmW_bf) {
  int tid = threadIdx.x;
  if (blockIdx.x >= 1024) {
    const int n8 = 32000 * 1024 / 8;
    int stride = 512 * 256;
    for (int i = (blockIdx.x - 1024) * 256 + tid; i < n8; i += stride) {
      float4 a = ((const float4*)lmW)[2 * i];
      float4 b = ((const float4*)lmW)[2 * i + 1];
      ushort4 lo, hi;
      lo.x = f32_to_bf16_rne(a.x); lo.y = f32_to_bf16_rne(a.y);
      lo.z = f32_to_bf16_rne(a.z); lo.w = f32_to_bf16_rne(a.w);
      hi.x = f32_to_bf16_rne(b.x); hi.y = f32_to_bf16_rne(b.y);
      hi.z = f32_to_bf16_rne(b.z); hi.w = f32_to_bf16_rne(b.w);
      ((ushort4*)lmW_bf)[2 * i] = lo;
      ((ushort4*)lmW_bf)[2 * i + 1] = hi;
    }
    return;
  }
  __shared__ float At[32][68];
  __shared__ float Bt[32][68];
  __shared__ int stok[64];
  int tm = blockIdx.x & 63;
  int tn = blockIdx.x >> 6;
  int r0 = tm * 64, j0 = tn * 64;
  if (tid < 64) stok[tid] = tok[r0 + tid];
  int tx = tid & 15, ty = tid >> 4;
  float acc[4][4] = {};
  for (int kt = 0; kt < 512; kt += 32) {
    __syncthreads();
    #pragma unroll
    for (int ii = 0; ii < 2; ++ii) {
      int idx = tid * 2 + ii;
      int m = idx >> 3, fv = idx & 7;
      float4 va = *(const float4*)&emb[(size_t)stok[m] * 512 + kt + fv * 4];
      float4 vb = *(const float4*)&Wx[(size_t)(j0 + m) * 512 + kt + fv * 4];
      At[fv * 4 + 0][m] = va.x; At[fv * 4 + 1][m] = va.y;
      At[fv * 4 + 2][m] = va.z; At[fv * 4 + 3][m] = va.w;
      Bt[fv * 4 + 0][m] = vb.x; Bt[fv * 4 + 1][m] = vb.y;
      Bt[fv * 4 + 2][m] = vb.z; Bt[fv * 4 + 3][m] = vb.w;
    }
    __syncthreads();
    #pragma unroll
    for (int k = 0; k < 32; ++k) {
      float4 a4 = *(const float4*)&At[k][ty * 4];
      float4 b4 = *(const float4*)&Bt[k][tx * 4];
      float av[4] = {a4.x, a4.y, a4.z, a4.w};
      float bv[4] = {b4.x, b4.y, b4.z, b4.w};
      #pragma unroll
      for (int i = 0; i < 4; ++i)
        #pragma unroll
        for (int jj = 0; jj < 4; ++jj) acc[i][jj] = fmaf(av[i], bv[jj], acc[i][jj]);
    }
  }
  #pragma unroll
  for (int i = 0; i < 4; ++i) {
    size_t row = (size_t)(r0 + ty * 4 + i) * 1024 + j0 + tx * 4;
    #pragma unroll
    for (int jj = 0; jj < 4; ++jj)
      xw[row + jj] = acc[i][jj] + bias[j0 + tx * 4 + jj];
  }
}

// ---------- kernel 3: recurrence (R10: exact R8 structure + prevh register) ----------
// R9 post-mortem: LDS atomic fetch_add serialized 16 waves' RMWs on 64 addrs
// (+263us) -> reverted to pbuf stores + writer's serial 16-load reduce (457us
// proven). Pad path now uses prevh REGISTER (this thread computed row j's h at
// t-1): removes the hs[g][l] read AND its cross-wave reuse race.
// 256 WGs x 1024 thr. chain c = blk&15 (XCD-local under round-robin), wg g =
// blk>>4 owns rows g*64..+63. Wave w = k-slice [w*64,w*64+64); lane l = row.
// Sync: fused data+tag u64 poll (s_sleep), wave-local LDS share (no barrier),
// ONE barrier before writer reduce.
__global__ __launch_bounds__(1024, 4) void rec_kernel(const float* __restrict__ Wh,
                                                      const float* __restrict__ xw,
                                                      const int* __restrict__ tok,
                                                      unsigned long long* hcomb,  // [2][16][1024]
                                                      unsigned short* __restrict__ h_all) {
  int c = blockIdx.x & 15;
  int g = blockIdx.x >> 4;
  int tid = threadIdx.x;
  int w = tid >> 6;              // wave = k-slice index
  int l = tid & 63;              // lane = row within group (and poll index)
  int j = g * 64 + l;            // output row this lane computes

  const float* wb = Wh + (size_t)j * 1024 + w * 64;
#define LDW(i) f32x4 w##i = *(const f32x4*)(wb + i * 4);
  LDW(0) LDW(1) LDW(2) LDW(3) LDW(4) LDW(5) LDW(6) LDW(7)
  LDW(8) LDW(9) LDW(10) LDW(11) LDW(12) LDW(13) LDW(14) LDW(15)
#undef LDW

  __shared__ float hs[16][64];    // [slice][k-within-slice]
  __shared__ float pbuf[16][64];  // [slice][row] partial sums
  unsigned long long* hc0 = hcomb + (size_t)c * 1024;
  unsigned long long* hc1 = hcomb + 16 * 1024 + (size_t)c * 1024;
  bool writer = (w == 0);
  float prevh = 0.f;             // h_{t-1}[j] for this writer lane (h0 = 0)

  for (int t = 0; t < 256; ++t) {
    // writer prefetch (hides under the poll)
    float xv = 0.f;
    int tkn = 1;
    if (writer) {
      xv = xw[((size_t)c * 256 + t) * 1024 + j];
      tkn = tok[c * 256 + t];
    }
    // poll own slot (slot tid = h[w*64+l]): tag==t means data in the same 8B
    unsigned long long* src = ((t & 1) ? hc1 : hc0) + tid;
    unsigned long long v;
    int guard = 0;
    do {
      v = __hip_atomic_load(src, __ATOMIC_RELAXED, __HIP_MEMORY_SCOPE_AGENT);
      if ((unsigned int)(v >> 32) == (unsigned int)t) break;
      __builtin_amdgcn_s_sleep(1);
    } while (++guard < (1 << 20));  // fail loud (absmax), not hung
    hs[w][l] = __builtin_bit_cast(float, (unsigned int)v);
    // wave-local share: all 64 lanes' ds_writes complete at lgkmcnt(0); no barrier
    __asm__ volatile("s_waitcnt lgkmcnt(0)" ::: "memory");

    const float* hp = &hs[w][0];   // broadcast reads (same addr all lanes: free)
    f32x4 a0 = {0.f, 0.f, 0.f, 0.f}, a1 = a0, a2 = a0, a3 = a0;
#define FMAI(i, acc) { f32x4 h4 = *(const f32x4*)(hp + i * 4); acc += w##i * h4; }
    FMAI(0, a0) FMAI(1, a1) FMAI(2, a2) FMAI(3, a3)
    FMAI(4, a0) FMAI(5, a1) FMAI(6, a2) FMAI(7, a3)
    FMAI(8, a0) FMAI(9, a1) FMAI(10, a2) FMAI(11, a3)
    FMAI(12, a0) FMAI(13, a1) FMAI(14, a2) FMAI(15, a3)
#undef FMAI
    f32x4 aa = (a0 + a1) + (a2 + a3);
    pbuf[w][l] = (aa[0] + aa[1]) + (aa[2] + aa[3]);
    __asm__ volatile("s_waitcnt lgkmcnt(0)\n\ts_barrier" ::: "memory");

    if (writer) {
      float s = 0.f;
      #pragma unroll
      for (int q = 0; q < 16; ++q) s += pbuf[q][l];  // lanes stride 4B: 2-way, free
      float hnew;
      if (tkn != PAD_IDX) {
        float pre = xv + s;
        float e = __builtin_amdgcn_exp2f(pre * 2.8853900817779268f);  // exp(2x)
        hnew = 1.0f - 2.0f / (e + 1.0f);                              // tanh(x)
      } else {
        hnew = prevh;  // register: race-free old h of own row
      }
      prevh = hnew;
      unsigned long long pv =
          ((unsigned long long)(unsigned int)(t + 1) << 32) |
          (unsigned long long)__builtin_bit_cast(unsigned int, hnew);
      __hip_atomic_store((((t + 1) & 1) ? hc1 : hc0) + j, pv,
                         __ATOMIC_RELAXED, __HIP_MEMORY_SCOPE_AGENT);
      h_all[((size_t)c * 256 + t) * 1024 + j] = f32_to_bf16_rne(hnew);
    }
  }
}

// ---------- kernel 4: logits = h_all(bf16) @ lm_W(bf16)^T, f32 out ----------
// BM=256 BN=256 BK=64, 512 thr (8 waves 2Mx4N). 2 LDS stages, counted vmcnt(8).
// Tail dead-stage: 8 same-hot-line 16B loads (keeps vmcnt math, ~0 traffic).
__global__ __launch_bounds__(512) void gemm_kernel(const unsigned short* __restrict__ A,
                                                   const unsigned short* __restrict__ B,
                                                   float* __restrict__ C) {
  __shared__ unsigned short lds[2 * 32768];
  int tid = threadIdx.x;
  int lane = tid & 63, wave = tid >> 6;
  int bid = blockIdx.x;
  int wgid = (bid & 7) * 250 + (bid >> 3);   // bijective XCD swizzle (2000 = 8*250)
  int tm = wgid & 15, tn = wgid >> 4;
  int r0 = tm * 256, c0 = tn * 256;
  int wm = wave >> 2, wn = wave & 3;         // 2M x 4N

  auto STAGE = [&](int kt, int st) {
    unsigned short* bufA = (unsigned short*)lds + st * 32768;
    unsigned short* bufB = bufA + 16384;
    #pragma unroll
    for (int i = 0; i < 4; ++i) {
      int slot = i * 512 + tid;
      int row = slot >> 3, sg = slot & 7;
      int kg = sg ^ (row & 7);
      const unsigned short* ga = A + (size_t)(r0 + row) * 1024 + kt * 64 + kg * 8;
      load16_to_lds(ga, &bufA[(i * 512 + wave * 64) * 8]);
    }
    #pragma unroll
    for (int i = 0; i < 4; ++i) {
      int slot = i * 512 + tid;
      int row = slot >> 3, sg = slot & 7;
      int kg = sg ^ (row & 7);
      const unsigned short* gb = B + (size_t)(c0 + row) * 1024 + kt * 64 + kg * 8;
      load16_to_lds(gb, &bufB[(i * 512 + wave * 64) * 8]);
    }
  };

  f32x4 zero = {0.f, 0.f, 0.f, 0.f};
  f32x4 acc[8][4];
  #pragma unroll
  for (int i = 0; i < 8; ++i)
    #pragma unroll
    for (int jx = 0; jx < 4; ++jx) acc[i][jx] = zero;

  STAGE(0, 0);
  STAGE(1, 1);
  __asm__ volatile("s_waitcnt vmcnt(8)\n\ts_barrier" ::: "memory");  // tile0 landed

  for (int kt = 0; kt < 16; ++kt) {
    int st = kt & 1;
    const unsigned short* bufA = (const unsigned short*)lds + st * 32768;
    const unsigned short* bufB = bufA + 16384;

    short8 af[8][2], bf[4][2];
    #pragma unroll
    for (int kkb = 0; kkb < 2; ++kkb) {
      int kbyte = kkb * 64 + (lane >> 4) * 16;
      #pragma unroll
      for (int i = 0; i < 8; ++i) {
        int rowa = wm * 128 + i * 16 + (lane & 15);
        af[i][kkb] = *(const short8*)((const char*)bufA + rowa * 128 + (kbyte ^ ((rowa & 7) << 4)));
      }
      #pragma unroll
      for (int i = 0; i < 4; ++i) {
        int rowb = wn * 64 + i * 16 + (lane & 15);
        bf[i][kkb] = *(const short8*)((const char*)bufB + rowb * 128 + (kbyte ^ ((rowb & 7) << 4)));
      }
    }
    // all waves' ds_reads of this buffer must retire before restaging into it
    __asm__ volatile("s_waitcnt lgkmcnt(0)\n\ts_barrier" ::: "memory");
    if (kt < 14) {
      STAGE(kt + 2, st);
    } else {
      // dead-stage: 8 loads of one hot 16B line into the retired buffer (vmcnt math)
      unsigned short* dead = (unsigned short*)lds + st * 32768;
      #pragma unroll
      for (int i = 0; i < 8; ++i) load16_to_lds(A + (size_t)r0 * 1024, &dead[i * 8]);
    }
    __builtin_amdgcn_s_setprio(1);
    #pragma unroll
    for (int kkb = 0; kkb < 2; ++kkb)
      #pragma unroll
      for (int i = 0; i < 8; ++i)
        #pragma unroll
        for (int jx = 0; jx < 4; ++jx)
          acc[i][jx] = __builtin_amdgcn_mfma_f32_16x16x32_bf16(af[i][kkb], bf[jx][kkb], acc[i][jx], 0, 0, 0);
    __builtin_amdgcn_s_setprio(0);
    __asm__ volatile("s_waitcnt vmcnt(8)\n\ts_barrier" ::: "memory");
  }
  // drain ALL outstanding LDS-DMA before this WG can retire (LDS reassignment!)
  __asm__ volatile("s_waitcnt vmcnt(0)" ::: "memory");

  int rbase = r0 + wm * 128 + (lane >> 4) * 4;
  int cbase = c0 + wn * 64 + (lane & 15);
  #pragma unroll
  for (int i = 0; i < 8; ++i)
    #pragma unroll
    for (int jx = 0; jx < 4; ++jx)
      #pragma unroll
      for (int q = 0; q < 4; ++q)
        C[(size_t)(rbase + i * 16 + q) * 32000 + cbase + jx * 16] = acc[i][jx][q];
}

// ---------- launch ----------
extern "C" void kernel_launch(void* const* d_in, const int* in_sizes, int n_in,
                              void* d_out, int out_size, void* d_ws, size_t ws_size,
                              hipStream_t stream) {
  const int* tok = (const int*)d_in[0];
  const float* emb = (const float*)d_in[1];
  const float* Wx = (const float*)d_in[2];
  const float* Wh = (const float*)d_in[3];
  const float* bias = (const float*)d_in[4];
  const float* lmW = (const float*)d_in[5];
  float* out = (float*)d_out;

  const size_t OFF_LMW = 0;                       // bf16 lm_W: 65,536,000
  const size_t OFF_XW = 65536000;                 // f32 xw:   16,777,216
  const size_t OFF_HALL = OFF_XW + 16777216;      // bf16 h_all: 8,388,608
  const size_t OFF_HCMB = OFF_HALL + 8388608;     // u64 hcomb: 262,144
  const size_t NEED = OFF_HCMB + 262144;
  if (ws_size < NEED) {
    sentinel_kernel<<<1, 1, 0, stream>>>(out);
    return;
  }
  char* ws = (char*)d_ws;
  unsigned short* lmW_bf = (unsigned short*)(ws + OFF_LMW);
  float* xw = (float*)(ws + OFF_XW);
  unsigned short* h_all = (unsigned short*)(ws + OFF_HALL);
  unsigned long long* hcomb = (unsigned long long*)(ws + OFF_HCMB);

  // tags must restart at 0 EVERY call (graph replay!)
  hipMemsetAsync(ws + OFF_HCMB, 0, 262144, stream);
  xwcvt_kernel<<<1536, 256, 0, stream>>>(tok, emb, Wx, bias, xw, lmW, lmW_bf);
  rec_kernel<<<256, 1024, 0, stream>>>(Wh, xw, tok, hcomb, h_all);
  gemm_kernel<<<2000, 512, 0, stream>>>(h_all, lmW_bf, out);
}

// Round 11
// 873.895 us; speedup vs baseline: 1.3101x; 1.0059x over previous
//
#include <hip/hip_runtime.h>

#define PAD_IDX 0

typedef __attribute__((ext_vector_type(8))) short short8;
typedef __attribute__((ext_vector_type(4))) float f32x4;

// ---------- helpers ----------
__device__ __forceinline__ unsigned short f32_to_bf16_rne(float f) {
  unsigned int u = __builtin_bit_cast(unsigned int, f);
  u += 0x7FFFu + ((u >> 16) & 1u);
  return (unsigned short)(u >> 16);
}

__device__ __forceinline__ void load16_to_lds(const void* g, void* lds) {
  __builtin_amdgcn_global_load_lds(
      (const __attribute__((address_space(1))) unsigned int*)g,
      (__attribute__((address_space(3))) unsigned int*)lds,
      16, 0, 0);
}

// ---------- kernel 0: sentinel (only if ws too small) ----------
__global__ void sentinel_kernel(float* out) { out[0] = 1.0e6f; }

// ---------- kernel 1: xw[r][j] = emb[tok[r]] . Wx[j] + bias[j]  (f32) ----------
__global__ __launch_bounds__(256) void xw_kernel(const int* __restrict__ tok,
                                                 const float* __restrict__ emb,
                                                 const float* __restrict__ Wx,
                                                 const float* __restrict__ bias,
                                                 float* __restrict__ xw) {
  __shared__ float At[32][68];
  __shared__ float Bt[32][68];
  __shared__ int stok[64];
  int tid = threadIdx.x;
  int tm = blockIdx.x & 63;
  int tn = blockIdx.x >> 6;
  int r0 = tm * 64, j0 = tn * 64;
  if (tid < 64) stok[tid] = tok[r0 + tid];
  int tx = tid & 15, ty = tid >> 4;
  float acc[4][4] = {};
  for (int kt = 0; kt < 512; kt += 32) {
    __syncthreads();
    #pragma unroll
    for (int ii = 0; ii < 2; ++ii) {
      int idx = tid * 2 + ii;
      int m = idx >> 3, fv = idx & 7;
      float4 va = *(const float4*)&emb[(size_t)stok[m] * 512 + kt + fv * 4];
      float4 vb = *(const float4*)&Wx[(size_t)(j0 + m) * 512 + kt + fv * 4];
      At[fv * 4 + 0][m] = va.x; At[fv * 4 + 1][m] = va.y;
      At[fv * 4 + 2][m] = va.z; At[fv * 4 + 3][m] = va.w;
      Bt[fv * 4 + 0][m] = vb.x; Bt[fv * 4 + 1][m] = vb.y;
      Bt[fv * 4 + 2][m] = vb.z; Bt[fv * 4 + 3][m] = vb.w;
    }
    __syncthreads();
    #pragma unroll
    for (int k = 0; k < 32; ++k) {
      float4 a4 = *(const float4*)&At[k][ty * 4];
      float4 b4 = *(const float4*)&Bt[k][tx * 4];
      float av[4] = {a4.x, a4.y, a4.z, a4.w};
      float bv[4] = {b4.x, b4.y, b4.z, b4.w};
      #pragma unroll
      for (int i = 0; i < 4; ++i)
        #pragma unroll
        for (int jj = 0; jj < 4; ++jj) acc[i][jj] = fmaf(av[i], bv[jj], acc[i][jj]);
    }
  }
  #pragma unroll
  for (int i = 0; i < 4; ++i) {
    size_t row = (size_t)(r0 + ty * 4 + i) * 1024 + j0 + tx * 4;
    #pragma unroll
    for (int jj = 0; jj < 4; ++jj)
      xw[row + jj] = acc[i][jj] + bias[j0 + tx * 4 + jj];
  }
}

// ---------- kernel 3: recurrence (R10 proven structure + cvt fold) ----------
// 256 WGs x 1024 thr. chain c = blk&15, wg g = blk>>4 (rows g*64..+63).
// Wave w = k-slice [w*64,+64); lane l = row. Fused data+tag u64 poll (s_sleep),
// wave-local LDS share (lgkmcnt0, no barrier), ONE barrier, writer reduce.
// R11: lm_W f32->bf16 conversion folded into poll slack: 1 float4/thread/step
// for t<32 (8.192M float4 total, exact). Loads issued AFTER poll success (any
// VMEM outstanding across the poll gets drained by the poll's vmcnt waits).
__global__ __launch_bounds__(1024, 4) void rec_kernel(const float* __restrict__ Wh,
                                                      const float* __restrict__ xw,
                                                      const int* __restrict__ tok,
                                                      unsigned long long* hcomb,  // [2][16][1024]
                                                      unsigned short* __restrict__ h_all,
                                                      const float* __restrict__ lmW,
                                                      unsigned short* __restrict__ lmW_bf) {
  int c = blockIdx.x & 15;
  int g = blockIdx.x >> 4;
  int tid = threadIdx.x;
  int w = tid >> 6;
  int l = tid & 63;
  int j = g * 64 + l;

  const float* wb = Wh + (size_t)j * 1024 + w * 64;
#define LDW(i) f32x4 w##i = *(const f32x4*)(wb + i * 4);
  LDW(0) LDW(1) LDW(2) LDW(3) LDW(4) LDW(5) LDW(6) LDW(7)
  LDW(8) LDW(9) LDW(10) LDW(11) LDW(12) LDW(13) LDW(14) LDW(15)
#undef LDW

  __shared__ float hs[16][64];
  __shared__ float pbuf[16][64];
  unsigned long long* hc0 = hcomb + (size_t)c * 1024;
  unsigned long long* hc1 = hcomb + 16 * 1024 + (size_t)c * 1024;
  bool writer = (w == 0);
  float prevh = 0.f;

  for (int t = 0; t < 256; ++t) {
    // poll own slot: tag==t means step-t data present in the same 8B load
    unsigned long long* src = ((t & 1) ? hc1 : hc0) + tid;
    unsigned long long v;
    int guard = 0;
    do {
      v = __hip_atomic_load(src, __ATOMIC_RELAXED, __HIP_MEMORY_SCOPE_AGENT);
      if ((unsigned int)(v >> 32) == (unsigned int)t) break;
      __builtin_amdgcn_s_sleep(1);
    } while (++guard < (1 << 20));  // fail loud (absmax), not hung

    // post-poll loads: latency hides under share+FMA (never spans a poll)
    float xv = 0.f;
    int tkn = 1;
    if (writer) {
      xv = xw[((size_t)c * 256 + t) * 1024 + j];
      tkn = tok[c * 256 + t];
    }
    float4 cva;
    size_t fi = 0;
    bool do_cvt = false;
    if (t < 32) {
      fi = (size_t)t * 262144 + ((size_t)blockIdx.x << 10) + tid;
      if (fi < 8192000) { cva = ((const float4*)lmW)[fi]; do_cvt = true; }
    }

    hs[w][l] = __builtin_bit_cast(float, (unsigned int)v);
    __asm__ volatile("s_waitcnt lgkmcnt(0)" ::: "memory");  // wave-local share

    const float* hp = &hs[w][0];   // broadcast reads
    f32x4 a0 = {0.f, 0.f, 0.f, 0.f}, a1 = a0, a2 = a0, a3 = a0;
#define FMAI(i, acc) { f32x4 h4 = *(const f32x4*)(hp + i * 4); acc += w##i * h4; }
    FMAI(0, a0) FMAI(1, a1) FMAI(2, a2) FMAI(3, a3)
    FMAI(4, a0) FMAI(5, a1) FMAI(6, a2) FMAI(7, a3)
    FMAI(8, a0) FMAI(9, a1) FMAI(10, a2) FMAI(11, a3)
    FMAI(12, a0) FMAI(13, a1) FMAI(14, a2) FMAI(15, a3)
#undef FMAI
    f32x4 aa = (a0 + a1) + (a2 + a3);
    pbuf[w][l] = (aa[0] + aa[1]) + (aa[2] + aa[3]);

    if (do_cvt) {
      ushort4 o;
      o.x = f32_to_bf16_rne(cva.x); o.y = f32_to_bf16_rne(cva.y);
      o.z = f32_to_bf16_rne(cva.z); o.w = f32_to_bf16_rne(cva.w);
      ((ushort4*)lmW_bf)[fi] = o;
    }
    __asm__ volatile("s_waitcnt lgkmcnt(0)\n\ts_barrier" ::: "memory");

    if (writer) {
      float s = 0.f;
      #pragma unroll
      for (int q = 0; q < 16; ++q) s += pbuf[q][l];
      float hnew;
      if (tkn != PAD_IDX) {
        float pre = xv + s;
        float e = __builtin_amdgcn_exp2f(pre * 2.8853900817779268f);  // exp(2x)
        hnew = 1.0f - 2.0f / (e + 1.0f);                              // tanh(x)
      } else {
        hnew = prevh;  // register: race-free old h of own row
      }
      prevh = hnew;
      unsigned long long pv =
          ((unsigned long long)(unsigned int)(t + 1) << 32) |
          (unsigned long long)__builtin_bit_cast(unsigned int, hnew);
      __hip_atomic_store((((t + 1) & 1) ? hc1 : hc0) + j, pv,
                         __ATOMIC_RELAXED, __HIP_MEMORY_SCOPE_AGENT);
      h_all[((size_t)c * 256 + t) * 1024 + j] = f32_to_bf16_rne(hnew);
    }
  }
}

// ---------- kernel 4: logits = h_all(bf16) @ lm_W(bf16)^T, f32 out ----------
// BM=256 BN=256 BK=64, 512 thr (8 waves 2Mx4N). 2 LDS stages, counted vmcnt(8).
// R11: L3-locality remap — XCD x (bid&7 under round-robin) owns Mtiles {2x,2x+1}
// (A panels L2-resident, 1MB); tm alternates fastest so each B panel is fetched
// once per XCD and reused by 2 WGs. L3 read ~0.5GB vs ~1.1GB (tm-fast scheme).
__global__ __launch_bounds__(512) void gemm_kernel(const unsigned short* __restrict__ A,
                                                   const unsigned short* __restrict__ B,
                                                   float* __restrict__ C) {
  __shared__ unsigned short lds[2 * 32768];
  int tid = threadIdx.x;
  int lane = tid & 63, wave = tid >> 6;
  int bid = blockIdx.x;
  int x = bid & 7;               // XCD under round-robin dispatch
  int r = bid >> 3;              // 0..249 within XCD
  int tm = 2 * x + (r & 1);      // XCD owns 2 A-panels; tm fastest
  int tn = r >> 1;               // 0..124; B panel reused by 2 consecutive WGs
  int r0 = tm * 256, c0 = tn * 256;
  int wm = wave >> 2, wn = wave & 3;  // 2M x 4N

  auto STAGE = [&](int kt, int st) {
    unsigned short* bufA = (unsigned short*)lds + st * 32768;
    unsigned short* bufB = bufA + 16384;
    #pragma unroll
    for (int i = 0; i < 4; ++i) {
      int slot = i * 512 + tid;
      int row = slot >> 3, sg = slot & 7;
      int kg = sg ^ (row & 7);
      const unsigned short* ga = A + (size_t)(r0 + row) * 1024 + kt * 64 + kg * 8;
      load16_to_lds(ga, &bufA[(i * 512 + wave * 64) * 8]);
    }
    #pragma unroll
    for (int i = 0; i < 4; ++i) {
      int slot = i * 512 + tid;
      int row = slot >> 3, sg = slot & 7;
      int kg = sg ^ (row & 7);
      const unsigned short* gb = B + (size_t)(c0 + row) * 1024 + kt * 64 + kg * 8;
      load16_to_lds(gb, &bufB[(i * 512 + wave * 64) * 8]);
    }
  };

  f32x4 zero = {0.f, 0.f, 0.f, 0.f};
  f32x4 acc[8][4];
  #pragma unroll
  for (int i = 0; i < 8; ++i)
    #pragma unroll
    for (int jx = 0; jx < 4; ++jx) acc[i][jx] = zero;

  STAGE(0, 0);
  STAGE(1, 1);
  __asm__ volatile("s_waitcnt vmcnt(8)\n\ts_barrier" ::: "memory");  // tile0 landed

  for (int kt = 0; kt < 16; ++kt) {
    int st = kt & 1;
    const unsigned short* bufA = (const unsigned short*)lds + st * 32768;
    const unsigned short* bufB = bufA + 16384;

    short8 af[8][2], bf[4][2];
    #pragma unroll
    for (int kkb = 0; kkb < 2; ++kkb) {
      int kbyte = kkb * 64 + (lane >> 4) * 16;
      #pragma unroll
      for (int i = 0; i < 8; ++i) {
        int rowa = wm * 128 + i * 16 + (lane & 15);
        af[i][kkb] = *(const short8*)((const char*)bufA + rowa * 128 + (kbyte ^ ((rowa & 7) << 4)));
      }
      #pragma unroll
      for (int i = 0; i < 4; ++i) {
        int rowb = wn * 64 + i * 16 + (lane & 15);
        bf[i][kkb] = *(const short8*)((const char*)bufB + rowb * 128 + (kbyte ^ ((rowb & 7) << 4)));
      }
    }
    // all waves' ds_reads of this buffer must retire before restaging into it
    __asm__ volatile("s_waitcnt lgkmcnt(0)\n\ts_barrier" ::: "memory");
    if (kt < 14) {
      STAGE(kt + 2, st);
    } else {
      // dead-stage: 8 loads of one hot 16B line into the retired buffer (vmcnt math)
      unsigned short* dead = (unsigned short*)lds + st * 32768;
      #pragma unroll
      for (int i = 0; i < 8; ++i) load16_to_lds(A + (size_t)r0 * 1024, &dead[i * 8]);
    }
    __builtin_amdgcn_s_setprio(1);
    #pragma unroll
    for (int kkb = 0; kkb < 2; ++kkb)
      #pragma unroll
      for (int i = 0; i < 8; ++i)
        #pragma unroll
        for (int jx = 0; jx < 4; ++jx)
          acc[i][jx] = __builtin_amdgcn_mfma_f32_16x16x32_bf16(af[i][kkb], bf[jx][kkb], acc[i][jx], 0, 0, 0);
    __builtin_amdgcn_s_setprio(0);
    __asm__ volatile("s_waitcnt vmcnt(8)\n\ts_barrier" ::: "memory");
  }
  // drain ALL outstanding LDS-DMA before this WG can retire (LDS reassignment!)
  __asm__ volatile("s_waitcnt vmcnt(0)" ::: "memory");

  int rbase = r0 + wm * 128 + (lane >> 4) * 4;
  int cbase = c0 + wn * 64 + (lane & 15);
  #pragma unroll
  for (int i = 0; i < 8; ++i)
    #pragma unroll
    for (int jx = 0; jx < 4; ++jx)
      #pragma unroll
      for (int q = 0; q < 4; ++q)
        C[(size_t)(rbase + i * 16 + q) * 32000 + cbase + jx * 16] = acc[i][jx][q];
}

// ---------- launch ----------
extern "C" void kernel_launch(void* const* d_in, const int* in_sizes, int n_in,
                              void* d_out, int out_size, void* d_ws, size_t ws_size,
                              hipStream_t stream) {
  const int* tok = (const int*)d_in[0];
  const float* emb = (const float*)d_in[1];
  const float* Wx = (const float*)d_in[2];
  const float* Wh = (const float*)d_in[3];
  const float* bias = (const float*)d_in[4];
  const float* lmW = (const float*)d_in[5];
  float* out = (float*)d_out;

  const size_t OFF_LMW = 0;                       // bf16 lm_W: 65,536,000
  const size_t OFF_XW = 65536000;                 // f32 xw:   16,777,216
  const size_t OFF_HALL = OFF_XW + 16777216;      // bf16 h_all: 8,388,608
  const size_t OFF_HCMB = OFF_HALL + 8388608;     // u64 hcomb: 262,144
  const size_t NEED = OFF_HCMB + 262144;
  if (ws_size < NEED) {
    sentinel_kernel<<<1, 1, 0, stream>>>(out);
    return;
  }
  char* ws = (char*)d_ws;
  unsigned short* lmW_bf = (unsigned short*)(ws + OFF_LMW);
  float* xw = (float*)(ws + OFF_XW);
  unsigned short* h_all = (unsigned short*)(ws + OFF_HALL);
  unsigned long long* hcomb = (unsigned long long*)(ws + OFF_HCMB);

  // tags must restart at 0 EVERY call (graph replay!)
  hipMemsetAsync(ws + OFF_HCMB, 0, 262144, stream);
  xw_kernel<<<1024, 256, 0, stream>>>(tok, emb, Wx, bias, xw);
  rec_kernel<<<256, 1024, 0, stream>>>(Wh, xw, tok, hcomb, h_all, lmW, lmW_bf);
  gemm_kernel<<<2000, 512, 0, stream>>>(h_all, lmW_bf, out);
}